// Round 4
// baseline (475.699 us; speedup 1.0000x reference)
//
#include <hip/hip_runtime.h>
#include <math.h>

// Problem constants: B=2, L=256, H=512, NH=8, DH=64
// ws layout (floats): q[262144] k[262144] val[262144] g[2097152] ctx[262144]

// ---------------------------------------------------------------------------
// K-split GEMM: C[512,512] += A[512,512] @ W[512,512] (+ bias on slice 0).
// BM=32, BN=64, BK=16, 128 threads, 4x4 micro-tile, reg prefetch.
// blockIdx.z = proj*4 + kslice; each block covers K in [ks*128, ks*128+128).
// C must be zero-initialized before launch (hipMemsetAsync).
// Breaking the serial K-chain 4x: per-thread serial FMA drops 8192 -> 2048,
// and wave count rises to 12/CU (qkv) so the latency is actually hidden.
// ---------------------------------------------------------------------------
__global__ __launch_bounds__(128) void gemm512_ks(
    const float* __restrict__ A0, const float* __restrict__ W0,
    const float* __restrict__ b0, float* __restrict__ C0,
    const float* __restrict__ A1, const float* __restrict__ W1,
    const float* __restrict__ b1, float* __restrict__ C1,
    const float* __restrict__ A2, const float* __restrict__ W2,
    const float* __restrict__ b2, float* __restrict__ C2) {
  const int proj = blockIdx.z >> 2;
  const int ks   = blockIdx.z & 3;
  const float* A    = (proj == 0) ? A0 : (proj == 1) ? A1 : A2;
  const float* W    = (proj == 0) ? W0 : (proj == 1) ? W1 : W2;
  const float* bias = (proj == 0) ? b0 : (proj == 1) ? b1 : b2;
  float* C          = (proj == 0) ? C0 : (proj == 1) ? C1 : C2;

  __shared__ float As[16][32];  // [k][m]
  __shared__ float Bs[16][64];  // [k][n]
  const int t  = threadIdx.x;            // 0..127
  const int tx = t & 15, ty = t >> 4;    // tx: n-quad 0..15, ty: m-quad 0..7
  const int bm0 = blockIdx.y * 32, bn0 = blockIdx.x * 64;
  const int arow = t >> 2;               // 0..31 (A-stage m)
  const int akq  = (t & 3) << 2;         // A-stage k quad
  const int bk   = t >> 4;               // 0..7 (B-stage k; also k+8)
  const int bnq  = (t & 15) << 2;        // B-stage n quad
  const int kb0  = ks * 128;

  float acc[4][4] = {};
  float4 a4 = *(const float4*)&A[(bm0 + arow) * 512 + kb0 + akq];
  float4 w0 = *(const float4*)&W[(kb0 + bk) * 512 + bn0 + bnq];
  float4 w1 = *(const float4*)&W[(kb0 + bk + 8) * 512 + bn0 + bnq];
  for (int kt = 0; kt < 8; ++kt) {
    As[akq + 0][arow] = a4.x;
    As[akq + 1][arow] = a4.y;
    As[akq + 2][arow] = a4.z;
    As[akq + 3][arow] = a4.w;
    *(float4*)&Bs[bk][bnq] = w0;
    *(float4*)&Bs[bk + 8][bnq] = w1;
    __syncthreads();
    if (kt < 7) {  // prefetch next tile into registers (hide latency)
      const int kn = kb0 + (kt + 1) * 16;
      a4 = *(const float4*)&A[(bm0 + arow) * 512 + kn + akq];
      w0 = *(const float4*)&W[(kn + bk) * 512 + bn0 + bnq];
      w1 = *(const float4*)&W[(kn + bk + 8) * 512 + bn0 + bnq];
    }
#pragma unroll
    for (int k = 0; k < 16; ++k) {
      float4 av = *(const float4*)&As[k][ty * 4];
      float4 bv = *(const float4*)&Bs[k][tx * 4];
      acc[0][0] = fmaf(av.x, bv.x, acc[0][0]);
      acc[0][1] = fmaf(av.x, bv.y, acc[0][1]);
      acc[0][2] = fmaf(av.x, bv.z, acc[0][2]);
      acc[0][3] = fmaf(av.x, bv.w, acc[0][3]);
      acc[1][0] = fmaf(av.y, bv.x, acc[1][0]);
      acc[1][1] = fmaf(av.y, bv.y, acc[1][1]);
      acc[1][2] = fmaf(av.y, bv.z, acc[1][2]);
      acc[1][3] = fmaf(av.y, bv.w, acc[1][3]);
      acc[2][0] = fmaf(av.z, bv.x, acc[2][0]);
      acc[2][1] = fmaf(av.z, bv.y, acc[2][1]);
      acc[2][2] = fmaf(av.z, bv.z, acc[2][2]);
      acc[2][3] = fmaf(av.z, bv.w, acc[2][3]);
      acc[3][0] = fmaf(av.w, bv.x, acc[3][0]);
      acc[3][1] = fmaf(av.w, bv.y, acc[3][1]);
      acc[3][2] = fmaf(av.w, bv.z, acc[3][2]);
      acc[3][3] = fmaf(av.w, bv.w, acc[3][3]);
    }
    __syncthreads();
  }
  // bias carried by slice 0 only; all slices atomically accumulate
  if (ks == 0) {
    float4 bb = *(const float4*)&bias[bn0 + tx * 4];
#pragma unroll
    for (int r = 0; r < 4; ++r) {
      acc[r][0] += bb.x;
      acc[r][1] += bb.y;
      acc[r][2] += bb.z;
      acc[r][3] += bb.w;
    }
  }
#pragma unroll
  for (int r = 0; r < 4; ++r) {
    float* crow = &C[(size_t)(bm0 + ty * 4 + r) * 512 + bn0 + tx * 4];
    atomicAdd(crow + 0, acc[r][0]);
    atomicAdd(crow + 1, acc[r][1]);
    atomicAdd(crow + 2, acc[r][2]);
    atomicAdd(crow + 3, acc[r][3]);
  }
}

// ---------------------------------------------------------------------------
// g[b,i,n,e] = sum_d Wr[e, n*64+d] * (q[b,i,n*64+d] + v[n,d])
// grid: (bi_tile=8, e_tile=8, n=8); K=64 fully staged.
// ---------------------------------------------------------------------------
__global__ __launch_bounds__(256) void g_gemm_k(const float* __restrict__ q,
                                                const float* __restrict__ vbias,
                                                const float* __restrict__ Wr,
                                                float* __restrict__ g) {
  __shared__ float As[64][64];  // [d][m]  qv
  __shared__ float Bs[64][64];  // [d][e]  Wr^T slice
  const int t   = threadIdx.x;
  const int bi0 = blockIdx.x * 64;
  const int eb  = blockIdx.y * 64;
  const int n   = blockIdx.z;
  const int row = t >> 2;        // 0..63
  const int dq  = (t & 3) << 4;  // 0,16,32,48
#pragma unroll
  for (int s = 0; s < 4; ++s) {
    int d = dq + s * 4;
    float4 a4 = *(const float4*)&q[(size_t)(bi0 + row) * 512 + n * 64 + d];
    float4 v4 = *(const float4*)&vbias[n * 64 + d];
    As[d + 0][row] = a4.x + v4.x;
    As[d + 1][row] = a4.y + v4.y;
    As[d + 2][row] = a4.z + v4.z;
    As[d + 3][row] = a4.w + v4.w;
    float4 b4 = *(const float4*)&Wr[(size_t)(eb + row) * 512 + n * 64 + d];
    Bs[d + 0][row] = b4.x;
    Bs[d + 1][row] = b4.y;
    Bs[d + 2][row] = b4.z;
    Bs[d + 3][row] = b4.w;
  }
  __syncthreads();
  const int tx = t & 15, ty = t >> 4;
  float acc[4][4] = {};
#pragma unroll 8
  for (int d = 0; d < 64; ++d) {
    float4 av = *(const float4*)&As[d][ty * 4];
    float4 bv = *(const float4*)&Bs[d][tx * 4];
    acc[0][0] = fmaf(av.x, bv.x, acc[0][0]);
    acc[0][1] = fmaf(av.x, bv.y, acc[0][1]);
    acc[0][2] = fmaf(av.x, bv.z, acc[0][2]);
    acc[0][3] = fmaf(av.x, bv.w, acc[0][3]);
    acc[1][0] = fmaf(av.y, bv.x, acc[1][0]);
    acc[1][1] = fmaf(av.y, bv.y, acc[1][1]);
    acc[1][2] = fmaf(av.y, bv.z, acc[1][2]);
    acc[1][3] = fmaf(av.y, bv.w, acc[1][3]);
    acc[2][0] = fmaf(av.z, bv.x, acc[2][0]);
    acc[2][1] = fmaf(av.z, bv.y, acc[2][1]);
    acc[2][2] = fmaf(av.z, bv.z, acc[2][2]);
    acc[2][3] = fmaf(av.z, bv.w, acc[2][3]);
    acc[3][0] = fmaf(av.w, bv.x, acc[3][0]);
    acc[3][1] = fmaf(av.w, bv.y, acc[3][1]);
    acc[3][2] = fmaf(av.w, bv.z, acc[3][2]);
    acc[3][3] = fmaf(av.w, bv.w, acc[3][3]);
  }
#pragma unroll
  for (int r = 0; r < 4; ++r) {
    float4 o = {acc[r][0], acc[r][1], acc[r][2], acc[r][3]};
    *(float4*)&g[((size_t)(bi0 + ty * 4 + r) * 8 + n) * 512 + eb + tx * 4] = o;
  }
}

// ---------------------------------------------------------------------------
// Fused scores + softmax + PV. One block of 512 threads per (b,i).
// Wave w (0..7) owns j in [32w, 32w+32). Lane l owns e-slice [8l, 8l+8).
// j >= seq_len[b]+lex_num are skipped entirely (score = -1e15, prob = 0).
// ---------------------------------------------------------------------------
__global__ __launch_bounds__(512, 4) void attn_k(
    const float* __restrict__ q, const float* __restrict__ kk,
    const float* __restrict__ g, const float* __restrict__ rpe,
    const float* __restrict__ u, const float* __restrict__ v,
    const float* __restrict__ br, const int* __restrict__ seq_len,
    const int* __restrict__ lex_num, const float* __restrict__ val,
    float* __restrict__ ctx) {
  const int bi = blockIdx.x;
  const int b = bi >> 8;
  const int t = threadIdx.x;
  const int lane = t & 63, w = t >> 6;   // 8 waves
  const int grp = lane >> 3, sub = lane & 7;
  const int e0 = lane << 3;
  __shared__ float sc[8][256];   // scores then probabilities
  __shared__ float cterm[8];     // br . (q+v) per head
  const int limit = seq_len[b] + lex_num[0];   // 128..256

  // per-lane (q+u) slice
  float qu[8];
  {
    const float* qrow = q + (size_t)bi * 512 + e0;
    float4 q0 = *(const float4*)qrow;
    float4 q1 = *(const float4*)(qrow + 4);
    float4 u0 = *(const float4*)(u + e0);
    float4 u1 = *(const float4*)(u + e0 + 4);
    qu[0] = q0.x + u0.x; qu[1] = q0.y + u0.y; qu[2] = q0.z + u0.z; qu[3] = q0.w + u0.w;
    qu[4] = q1.x + u1.x; qu[5] = q1.y + u1.y; qu[6] = q1.z + u1.z; qu[7] = q1.w + u1.w;
  }
  // g fragments in registers: gf[head][8]
  float gf[8][8];
#pragma unroll
  for (int n = 0; n < 8; ++n) {
    const float* grow = g + ((size_t)bi * 8 + n) * 512 + e0;
    float4 ga = *(const float4*)grow;
    float4 gb = *(const float4*)(grow + 4);
    gf[n][0] = ga.x; gf[n][1] = ga.y; gf[n][2] = ga.z; gf[n][3] = ga.w;
    gf[n][4] = gb.x; gf[n][5] = gb.y; gf[n][6] = gb.z; gf[n][7] = gb.w;
  }
  if (w == 0) {  // br . (q+v) per head (zero here; kept for generality)
    const float* qrow = q + (size_t)bi * 512 + e0;
    float4 q0 = *(const float4*)qrow;
    float4 q1 = *(const float4*)(qrow + 4);
    float4 v0 = *(const float4*)(v + e0);
    float4 v1 = *(const float4*)(v + e0 + 4);
    float4 r0 = *(const float4*)(br + e0);
    float4 r1 = *(const float4*)(br + e0 + 4);
    float p = (q0.x + v0.x) * r0.x;
    p = fmaf(q0.y + v0.y, r0.y, p);
    p = fmaf(q0.z + v0.z, r0.z, p);
    p = fmaf(q0.w + v0.w, r0.w, p);
    p = fmaf(q1.x + v1.x, r1.x, p);
    p = fmaf(q1.y + v1.y, r1.y, p);
    p = fmaf(q1.z + v1.z, r1.z, p);
    p = fmaf(q1.w + v1.w, r1.w, p);
    p += __shfl_xor(p, 1);
    p += __shfl_xor(p, 2);
    p += __shfl_xor(p, 4);
    if (sub == 0) cterm[grp] = p;
  }
  __syncthreads();
  const float ct = (lane < 8) ? cterm[lane] : 0.0f;

  const int jbase = w * 32;
  int jend = limit - jbase;
  jend = jend < 0 ? 0 : (jend > 32 ? 32 : jend);
  // masked tail: scores are the constant -1e15, no memory needed
  if (lane < 8) {
    for (int jj = jend; jj < 32; ++jj) sc[lane][jbase + jj] = -1e15f;
  }

  const int s1 = sub & 1, s2 = (sub >> 1) & 1, s4 = (sub >> 2) & 1;
  const float* rbase = rpe + (size_t)bi * 256 * 512;
  const float* kbase = kk + (size_t)b * 256 * 512;
#pragma unroll 2
  for (int jj = 0; jj < jend; ++jj) {
    const int j = jbase + jj;
    const float* rrow = rbase + (size_t)j * 512 + e0;
    const float* krow = kbase + (size_t)j * 512 + e0;
    float4 r0 = *(const float4*)rrow;
    float4 r1 = *(const float4*)(rrow + 4);
    float4 k0 = *(const float4*)krow;
    float4 k1 = *(const float4*)(krow + 4);
    // AC partial for this lane's head
    float kd = qu[0] * k0.x;
    kd = fmaf(qu[1], k0.y, kd);
    kd = fmaf(qu[2], k0.z, kd);
    kd = fmaf(qu[3], k0.w, kd);
    kd = fmaf(qu[4], k1.x, kd);
    kd = fmaf(qu[5], k1.y, kd);
    kd = fmaf(qu[6], k1.z, kd);
    kd = fmaf(qu[7], k1.w, kd);
    float a[8];
#pragma unroll
    for (int n = 0; n < 8; ++n) {
      float s = r0.x * gf[n][0];
      s = fmaf(r0.y, gf[n][1], s);
      s = fmaf(r0.z, gf[n][2], s);
      s = fmaf(r0.w, gf[n][3], s);
      s = fmaf(r1.x, gf[n][4], s);
      s = fmaf(r1.y, gf[n][5], s);
      s = fmaf(r1.z, gf[n][6], s);
      s = fmaf(r1.w, gf[n][7], s);
      a[n] = s + ((grp == n) ? kd : 0.0f);  // fold AC into head grp's slot
    }
    // transpose-reduce: lane ends with head (lane&7)'s wave-wide sum
    float b0 = (s1 ? a[1] : a[0]) + __shfl_xor(s1 ? a[0] : a[1], 1);
    float b1 = (s1 ? a[3] : a[2]) + __shfl_xor(s1 ? a[2] : a[3], 1);
    float b2 = (s1 ? a[5] : a[4]) + __shfl_xor(s1 ? a[4] : a[5], 1);
    float b3 = (s1 ? a[7] : a[6]) + __shfl_xor(s1 ? a[6] : a[7], 1);
    float c0 = (s2 ? b1 : b0) + __shfl_xor(s2 ? b0 : b1, 2);
    float c1 = (s2 ? b3 : b2) + __shfl_xor(s2 ? b2 : b3, 2);
    float tot = (s4 ? c1 : c0) + __shfl_xor(s4 ? c0 : c1, 4);
    tot += __shfl_xor(tot, 8);
    tot += __shfl_xor(tot, 16);
    tot += __shfl_xor(tot, 32);
    if (lane < 8) sc[lane][j] = (tot + ct) * 0.125f;
  }
  __syncthreads();

  // softmax in-place: wave w handles head w
  {
    const int n = w;
    float x0 = sc[n][lane], x1 = sc[n][lane + 64];
    float x2 = sc[n][lane + 128], x3 = sc[n][lane + 192];
    float m = fmaxf(fmaxf(x0, x1), fmaxf(x2, x3));
#pragma unroll
    for (int off = 1; off < 64; off <<= 1) m = fmaxf(m, __shfl_xor(m, off));
    float e0v = __expf(x0 - m), e1v = __expf(x1 - m);
    float e2v = __expf(x2 - m), e3v = __expf(x3 - m);
    float s = e0v + e1v + e2v + e3v;
#pragma unroll
    for (int off = 1; off < 64; off <<= 1) s += __shfl_xor(s, off);
    float inv = 1.0f / s;
    sc[n][lane] = e0v * inv;
    sc[n][lane + 64] = e1v * inv;
    sc[n][lane + 128] = e2v * inv;
    sc[n][lane + 192] = e3v * inv;
  }
  __syncthreads();

  // PV: thread t owns channel c = t; probs are 0 for j >= limit -> bound loop
  const int c = t;
  const int n = t >> 6;
  float acc = 0.0f;
  const float* vb = val + (size_t)b * 256 * 512 + c;
#pragma unroll 4
  for (int j = 0; j < limit; ++j) {
    acc = fmaf(sc[n][j], vb[(size_t)j * 512], acc);
  }
  ctx[(size_t)bi * 512 + c] = acc;
}

// ---------------------------------------------------------------------------
extern "C" void kernel_launch(void* const* d_in, const int* in_sizes, int n_in,
                              void* d_out, int out_size, void* d_ws, size_t ws_size,
                              hipStream_t stream) {
  const float* key     = (const float*)d_in[0];
  const float* query   = (const float*)d_in[1];
  const float* value   = (const float*)d_in[2];
  const int* seq_len   = (const int*)d_in[3];
  const int* lex_num   = (const int*)d_in[4];
  // d_in[5] pos_s, d_in[6] pos_e: unused by reference
  const float* rpe     = (const float*)d_in[7];
  const float* Wk      = (const float*)d_in[8];
  const float* bk      = (const float*)d_in[9];
  const float* Wq      = (const float*)d_in[10];
  const float* bq      = (const float*)d_in[11];
  const float* Wv      = (const float*)d_in[12];
  const float* bv      = (const float*)d_in[13];
  const float* Wr      = (const float*)d_in[14];
  const float* br      = (const float*)d_in[15];
  const float* u       = (const float*)d_in[16];
  const float* v       = (const float*)d_in[17];
  const float* Wf      = (const float*)d_in[18];
  const float* bf      = (const float*)d_in[19];
  float* out = (float*)d_out;

  float* ws     = (float*)d_ws;
  float* q_ws   = ws;                  // 262144
  float* k_ws   = q_ws + 262144;       // 262144
  float* val_ws = k_ws + 262144;       // 262144
  float* g_ws   = val_ws + 262144;     // 2097152
  float* ctx_ws = g_ws + 2097152;      // 262144

  // zero-init K-split accumulation targets (graph-capture-safe async memsets)
  hipMemsetAsync(q_ws, 0, 3 * 262144 * sizeof(float), stream);   // q,k,val
  hipMemsetAsync(d_out, 0, (size_t)out_size * sizeof(float), stream);

  // q/k/v projections: K-split x4 -> 1536 blocks, 12 waves/CU
  gemm512_ks<<<dim3(8, 16, 12), dim3(128), 0, stream>>>(query, Wq, bq, q_ws,
                                                        key, Wk, bk, k_ws,
                                                        value, Wv, bv, val_ws);
  // g = per-head Wr slice applied to (q + v_bias)
  g_gemm_k<<<dim3(8, 8, 8), dim3(256), 0, stream>>>(q_ws, v, Wr, g_ws);
  // fused scores + softmax + PV (streams masked rpe exactly once)
  attn_k<<<dim3(512), dim3(512), 0, stream>>>(q_ws, k_ws, g_ws, rpe, u, v, br,
                                              seq_len, lex_num, val_ws, ctx_ws);
  // final projection: K-split x4 -> 512 blocks
  gemm512_ks<<<dim3(8, 16, 4), dim3(128), 0, stream>>>(ctx_ws, Wf, bf, out,
                                                       ctx_ws, Wf, bf, out,
                                                       ctx_ws, Wf, bf, out);
}